// Round 3
// baseline (274.591 us; speedup 1.0000x reference)
//
#include <hip/hip_runtime.h>
#include <limits.h>
#include <stdint.h>

#define ALPHA 0.2f
static constexpr int N = 8192;
static constexpr int D = 128;
static constexpr int C = 512;
static constexpr int BT = 128;   // block tile (i and j)
static constexpr int KC = 64;    // k-chunk in fp16 elems
static constexpr int SL = 72;    // LDS row stride in fp16 (64 + 8 pad)
static constexpr int NPART = 4096;

using half8   = __attribute__((ext_vector_type(8))) _Float16;
using half2v  = __attribute__((ext_vector_type(2))) _Float16;
using floatx16 = __attribute__((ext_vector_type(16))) float;

__device__ __forceinline__ floatx16 zerov() { floatx16 v = {0.f}; return v; }

// ---------------- setup kernels ----------------

__global__ void k_init(int* anchor, int* cnt, int* cursor) {
    int t = threadIdx.x;
    if (t < C) { anchor[t] = INT_MAX; cnt[t] = 0; cursor[t] = 0; }
}

// one wave per row: fp16 convert + squared norm + label count/anchor-min (lane 0)
__global__ void k_prep(const float* __restrict__ x, const int* __restrict__ labels,
                       _Float16* __restrict__ xh, float* __restrict__ sq,
                       int* anchor, int* cnt) {
    int row = (blockIdx.x * blockDim.x + threadIdx.x) >> 6;
    int lane = threadIdx.x & 63;
    float2 v = ((const float2*)(x + (size_t)row * D))[lane];
    half2v h; h[0] = (_Float16)v.x; h[1] = (_Float16)v.y;
    *(half2v*)(xh + (size_t)row * D + lane * 2) = h;
    float s = v.x * v.x + v.y * v.y;
#pragma unroll
    for (int off = 32; off; off >>= 1) s += __shfl_down(s, off);
    if (lane == 0) {
        sq[row] = s;
        int c = labels[row];
        atomicMin(&anchor[c], row);
        atomicAdd(&cnt[c], 1);
    }
}

// single wave: parallel scan over 512 counts
__global__ void k_scan(const int* __restrict__ cnt, int* offs) {
    int lane = threadIdx.x;
    int v[8], local[8];
    int base = lane * 8;
#pragma unroll
    for (int t = 0; t < 8; ++t) v[t] = cnt[base + t];
    int run = 0;
#pragma unroll
    for (int t = 0; t < 8; ++t) { local[t] = run; run += v[t]; }
    int scan = run;
#pragma unroll
    for (int off = 1; off < 64; off <<= 1) {
        int o = __shfl_up(scan, off);
        if (lane >= off) scan += o;
    }
    int excl = scan - run;
#pragma unroll
    for (int t = 0; t < 8; ++t) offs[base + t] = excl + local[t];
    if (lane == 63) offs[C] = excl + run;
}

__global__ void k_scatter(const int* __restrict__ labels, const int* __restrict__ offs,
                          int* cursor, int* members) {
    int i = blockIdx.x * blockDim.x + threadIdx.x;
    if (i < N) {
        int c = labels[i];
        int p = offs[c] + atomicAdd(&cursor[c], 1);
        members[p] = i;
    }
}

// one wave per row: ap[i] = D(anchor(lab_i), i)  (fp32 exact path)
__global__ void k_ap(const float* __restrict__ x, const int* __restrict__ labels,
                     const int* __restrict__ anchor, const float* __restrict__ sq,
                     float* __restrict__ ap) {
    int i = (blockIdx.x * blockDim.x + threadIdx.x) >> 6;
    int lane = threadIdx.x & 63;
    int a = anchor[labels[i]];
    float2 vi = ((const float2*)(x + (size_t)i * D))[lane];
    float2 va = ((const float2*)(x + (size_t)a * D))[lane];
    float s = vi.x * va.x + vi.y * va.y;
#pragma unroll
    for (int off = 32; off; off >>= 1) s += __shfl_down(s, off);
    if (lane == 0) ap[i] = sq[a] + sq[i] - 2.0f * s;
}

// one wave per label group: rank-sort non-anchor ap values -> sorted list + prefix sums
__global__ void k_grpsort(const int* __restrict__ members, const int* __restrict__ offs,
                          const int* __restrict__ anchor, const float* __restrict__ ap,
                          float* __restrict__ grpap, float* __restrict__ grppre) {
    int c = blockIdx.x * 4 + (threadIdx.x >> 6);
    int lane = threadIdx.x & 63;
    int m0 = offs[c], m1 = offs[c + 1];
    int n = m1 - m0;                    // group size (Poisson(16); <=64 assumed)
    if (n <= 0) return;
    int a = anchor[c];
    float sval = 1e30f;                  // sort key (anchor & empty lanes sink)
    float rval = 0.f;
    int myidx = INT_MAX;
    bool isanc = true;
    if (lane < n) {
        int idx = members[m0 + lane];
        myidx = idx;
        isanc = (idx == a);
        rval = ap[idx];
        sval = isanc ? 1e30f : rval;
    }
    int rank = 0;
    float presum = 0.f;
    float total = 0.f;
#pragma unroll
    for (int l = 0; l < 64; ++l) {
        float ov = __shfl(sval, l);
        int oidx = __shfl(myidx, l);
        bool smaller = (ov < sval) || (ov == sval && oidx < myidx);
        if (smaller && ov < 1e29f) presum += ov;
        if (smaller) ++rank;
        if (ov < 1e29f) total += ov;
    }
    if (lane < n && !isanc) {
        grpap[m0 + rank] = rval;
        grppre[m0 + rank] = presum;
    }
    if (lane == 0) grppre[m0 + (n - 1)] = total;  // Pre(kl), kl = n-1
}

// ---------------- fused term1+term2: N x N Gram via MFMA ----------------

__device__ __forceinline__ void block_reduce_write(float local, float* slot, int tid) {
#pragma unroll
    for (int off = 32; off; off >>= 1) local += __shfl_down(local, off);
    __shared__ float wsum[4];
    if ((tid & 63) == 0) wsum[tid >> 6] = local;
    __syncthreads();
    if (tid == 0) *slot = wsum[0] + wsum[1] + wsum[2] + wsum[3];
}

__launch_bounds__(256)
__global__ void k_term2_fused(const _Float16* __restrict__ xh, const int* __restrict__ labels,
                              const int* __restrict__ anchor, const int* __restrict__ offs,
                              const float* __restrict__ sq, const float* __restrict__ ap,
                              const float* __restrict__ grpap, const float* __restrict__ grppre,
                              float* __restrict__ partials) {
    __shared__ __align__(16) _Float16 As[BT * SL];
    __shared__ __align__(16) _Float16 Bs[BT * SL];
    __shared__ float4 rowE[BT];    // (e_i|sq_i, lab bits, pack(st,kl)|-1, unused)
    __shared__ float2 colSL[BT];   // (sq_j, lab_j bits)

    const int i0 = blockIdx.x * BT;
    const int j0 = blockIdx.y * BT;
    const int tid = threadIdx.x;
    const int lane = tid & 63, w = tid >> 6;
    const int wr = w >> 1, wc = w & 1;
    const int m = lane & 31, q = lane >> 5;

    if (tid < BT) {
        int i = i0 + tid;
        int li = labels[i];
        int a = anchor[li];
        if (i == a) {
            // anchor row: term1 interval query over its group's sorted ap list
            int st = offs[li];
            int kl = offs[li + 1] - st - 1;     // # non-anchor members
            if (kl > 255) kl = 255;
            if (kl > 0)
                rowE[tid] = make_float4(sq[i], __int_as_float(li),
                                        __int_as_float((st << 8) | kl), 0.f);
            else
                rowE[tid] = make_float4(-1e30f, __int_as_float(li),
                                        __int_as_float(-1), 0.f);
        } else {
            // positive row: term2 hinge; t = 2*dot + (ap_i + alpha - sq_i - sq_j)
            rowE[tid] = make_float4(ap[i] + ALPHA - sq[i], __int_as_float(li),
                                    __int_as_float(-1), 0.f);
        }
    } else {
        int t = tid - BT;
        int j = j0 + t;
        colSL[t] = make_float2(sq[j], __int_as_float(labels[j]));
    }

    floatx16 acc[2][2];
    acc[0][0] = zerov(); acc[0][1] = zerov(); acc[1][0] = zerov(); acc[1][1] = zerov();

    const _Float16* Abase = &As[(wr * 64 + m) * SL + q * 8];
    const _Float16* Bbase = &Bs[(wc * 64 + m) * SL + q * 8];

    for (int kc = 0; kc < D; kc += KC) {
        __syncthreads();
#pragma unroll
        for (int it = 0; it < 4; ++it) {
            int f = tid + it * 256;
            int row = f >> 3, g = f & 7;
            half8 v = *(const half8*)(xh + (size_t)(i0 + row) * D + kc + g * 8);
            *(half8*)(&As[row * SL + g * 8]) = v;
            half8 u = *(const half8*)(xh + (size_t)(j0 + row) * D + kc + g * 8);
            *(half8*)(&Bs[row * SL + g * 8]) = u;
        }
        __syncthreads();
#pragma unroll
        for (int ks = 0; ks < KC; ks += 16) {
            half8 a0 = *(const half8*)(Abase + ks);
            half8 a1 = *(const half8*)(Abase + 32 * SL + ks);
            half8 b0 = *(const half8*)(Bbase + ks);
            half8 b1 = *(const half8*)(Bbase + 32 * SL + ks);
            acc[0][0] = __builtin_amdgcn_mfma_f32_32x32x16_f16(a0, b0, acc[0][0], 0, 0, 0);
            acc[0][1] = __builtin_amdgcn_mfma_f32_32x32x16_f16(a0, b1, acc[0][1], 0, 0, 0);
            acc[1][0] = __builtin_amdgcn_mfma_f32_32x32x16_f16(a1, b0, acc[1][0], 0, 0, 0);
            acc[1][1] = __builtin_amdgcn_mfma_f32_32x32x16_f16(a1, b1, acc[1][1], 0, 0, 0);
        }
    }

    float sqj[2]; int labj[2];
#pragma unroll
    for (int tn = 0; tn < 2; ++tn) {
        float2 cj = colSL[wc * 64 + tn * 32 + m];
        sqj[tn] = cj.x; labj[tn] = __float_as_int(cj.y);
    }

    float local = 0.f;
#pragma unroll
    for (int tm = 0; tm < 2; ++tm) {
        int rbase = wr * 64 + tm * 32 + 4 * q;
#pragma unroll
        for (int rr = 0; rr < 16; ++rr) {
            int row = rbase + (rr & 3) + 8 * (rr >> 2);
            float4 re = rowE[row];
            int labi = __float_as_int(re.y);
            int pk = __float_as_int(re.z);
#pragma unroll
            for (int tn = 0; tn < 2; ++tn) {
                if (labi == labj[tn]) continue;
                float dot = acc[tm][tn][rr];
                if (pk < 0) {
                    // term2 hinge: contributes t iff 0 < t < alpha
                    float t = fmaf(2.f, dot, re.x - sqj[tn]);
                    if (t > 0.f && t < ALPHA) local += t;
                } else {
                    // term1: S_c(v) = sum_{ap in (v-a, v)} (ap + a - v)
                    float v = fmaf(-2.f, dot, re.x + sqj[tn]);
                    int st = pk >> 8, kl = pk & 255;
                    int lo = 0, n = kl;
                    while (n > 0) {
                        int half = n >> 1;
                        bool go = grpap[st + lo + half] < v;
                        lo = go ? lo + half + 1 : lo;
                        n = go ? n - half - 1 : half;
                    }
                    int hv = lo;
                    float vl = v - ALPHA;
                    int lv = hv;
                    while (lv > 0 && grpap[st + lv - 1] > vl) --lv;
                    if (hv > lv) {
                        local += (grppre[st + hv] - grppre[st + lv])
                               + (ALPHA - v) * (float)(hv - lv);
                    }
                }
            }
        }
    }
    block_reduce_write(local, &partials[blockIdx.y * gridDim.x + blockIdx.x], tid);
}

__global__ void k_final(const float* __restrict__ partials, float* __restrict__ out) {
    __shared__ double sred[4];
    int tid = threadIdx.x, lane = tid & 63;
    double s = 0.0;
    for (int t = tid; t < NPART; t += 256) s += (double)partials[t];
#pragma unroll
    for (int off = 32; off; off >>= 1) s += __shfl_down(s, off);
    if (lane == 0) sred[tid >> 6] = s;
    __syncthreads();
    if (tid == 0) out[0] = (float)(sred[0] + sred[1] + sred[2] + sred[3]);
}

// ---------------- launch ----------------

extern "C" void kernel_launch(void* const* d_in, const int* in_sizes, int n_in,
                              void* d_out, int out_size, void* d_ws, size_t ws_size,
                              hipStream_t stream) {
    const float* x = (const float*)d_in[0];
    const int* labels = (const int*)d_in[1];
    float* out = (float*)d_out;

    char* p = (char*)d_ws;
    int* anchor = (int*)p;            p += C * 4;
    int* cnt = (int*)p;               p += C * 4;
    int* offs = (int*)p;              p += (C + 1) * 4;
    int* cursor = (int*)p;            p += C * 4;
    int* members = (int*)p;           p += N * 4;
    float* sq = (float*)p;            p += N * 4;
    float* ap = (float*)p;            p += N * 4;
    float* grpap = (float*)p;         p += (N + 8) * 4;
    float* grppre = (float*)p;        p += (N + 8) * 4;
    float* partials = (float*)p;      p += NPART * 4;
    p = (char*)(((uintptr_t)p + 255) & ~(uintptr_t)255);
    _Float16* xh = (_Float16*)p;      // N*D*2 bytes

    k_init<<<1, 512, 0, stream>>>(anchor, cnt, cursor);
    k_prep<<<N / 4, 256, 0, stream>>>(x, labels, xh, sq, anchor, cnt);
    k_scan<<<1, 64, 0, stream>>>(cnt, offs);
    k_scatter<<<N / 256, 256, 0, stream>>>(labels, offs, cursor, members);
    k_ap<<<N / 4, 256, 0, stream>>>(x, labels, anchor, sq, ap);
    k_grpsort<<<C / 4, 256, 0, stream>>>(members, offs, anchor, ap, grpap, grppre);

    dim3 g2(N / BT, N / BT);
    k_term2_fused<<<g2, 256, 0, stream>>>(xh, labels, anchor, offs, sq, ap,
                                          grpap, grppre, partials);
    k_final<<<1, 256, 0, stream>>>(partials, out);
}

// Round 4
// 149.721 us; speedup vs baseline: 1.8340x; 1.8340x over previous
//
#include <hip/hip_runtime.h>
#include <limits.h>
#include <stdint.h>

#define ALPHA 0.2f
static constexpr int N = 8192;
static constexpr int D = 128;
static constexpr int C = 512;
static constexpr int BT = 128;   // block tile (i and j)
static constexpr int KC = 32;    // k-chunk in fp16 elems
static constexpr int SL = 40;    // LDS row stride in fp16 (32 + 8 pad)
static constexpr int NPART = 4096;

using half8   = __attribute__((ext_vector_type(8))) _Float16;
using half2v  = __attribute__((ext_vector_type(2))) _Float16;
using floatx16 = __attribute__((ext_vector_type(16))) float;

__device__ __forceinline__ floatx16 zerov() { floatx16 v = {0.f}; return v; }

// ---------------- setup kernels ----------------

__global__ void k_init(int* anchor) {
    int t = threadIdx.x;
    if (t < C) anchor[t] = INT_MAX;
}

// one wave per row: fp16 convert + squared norm + anchor-min (lane 0)
__global__ void k_prep(const float* __restrict__ x, const int* __restrict__ labels,
                       _Float16* __restrict__ xh, float* __restrict__ sq, int* anchor) {
    int row = (blockIdx.x * blockDim.x + threadIdx.x) >> 6;
    int lane = threadIdx.x & 63;
    float2 v = ((const float2*)(x + (size_t)row * D))[lane];
    half2v h; h[0] = (_Float16)v.x; h[1] = (_Float16)v.y;
    *(half2v*)(xh + (size_t)row * D + lane * 2) = h;
    float s = v.x * v.x + v.y * v.y;
#pragma unroll
    for (int off = 32; off; off >>= 1) s += __shfl_down(s, off);
    if (lane == 0) {
        sq[row] = s;
        atomicMin(&anchor[labels[row]], row);
    }
}

// one wave per row: ap[i] = D(anchor(lab_i), i)  (fp32 exact path)
__global__ void k_ap(const float* __restrict__ x, const int* __restrict__ labels,
                     const int* __restrict__ anchor, const float* __restrict__ sq,
                     float* __restrict__ ap) {
    int i = (blockIdx.x * blockDim.x + threadIdx.x) >> 6;
    int lane = threadIdx.x & 63;
    int a = anchor[labels[i]];
    float2 vi = ((const float2*)(x + (size_t)i * D))[lane];
    float2 va = ((const float2*)(x + (size_t)a * D))[lane];
    float s = vi.x * va.x + vi.y * va.y;
#pragma unroll
    for (int off = 32; off; off >>= 1) s += __shfl_down(s, off);
    if (lane == 0) ap[i] = sq[a] + sq[i] - 2.0f * s;
}

// ---------------- fused term1+term2: dual-Gram MFMA, branch-free epilogue ----------------

__device__ __forceinline__ void block_reduce_write(float local, float* slot, int tid) {
#pragma unroll
    for (int off = 32; off; off >>= 1) local += __shfl_down(local, off);
    __shared__ float wsum[4];
    if ((tid & 63) == 0) wsum[tid >> 6] = local;
    __syncthreads();
    if (tid == 0) *slot = wsum[0] + wsum[1] + wsum[2] + wsum[3];
}

__launch_bounds__(256)
__global__ void k_fused(const _Float16* __restrict__ xh, const int* __restrict__ labels,
                        const int* __restrict__ anchor, const float* __restrict__ sq,
                        const float* __restrict__ ap, float* __restrict__ partials) {
    __shared__ __align__(16) _Float16 As[BT * SL];    // rows i0..
    __shared__ __align__(16) _Float16 A2s[BT * SL];   // anchor rows of lab(i0..)
    __shared__ __align__(16) _Float16 Bs[BT * SL];    // rows j0..
    __shared__ float4 rowE[BT];    // (e2 = ap+a-sq_i, e1 = ap+a-sq_anchor, lab bits, -)
    __shared__ float2 colSL[BT];   // (sq_j, lab_j bits)
    __shared__ int sAnc[BT];

    const int i0 = blockIdx.x * BT;
    const int j0 = blockIdx.y * BT;
    const int tid = threadIdx.x;
    const int lane = tid & 63, w = tid >> 6;
    const int wr = w >> 1, wc = w & 1;
    const int m = lane & 31, q = lane >> 5;

    if (tid < BT) {
        int i = i0 + tid;
        int li = labels[i];
        int a = anchor[li];
        sAnc[tid] = a;
        float e2, e1;
        if (i == a) { e2 = -1e30f; e1 = -1e30f; }   // anchors are not positives
        else {
            float base = ap[i] + ALPHA;
            e2 = base - sq[i];
            e1 = base - sq[a];
        }
        rowE[tid] = make_float4(e2, e1, __int_as_float(li), 0.f);
    } else {
        int t = tid - BT;
        int j = j0 + t;
        colSL[t] = make_float2(sq[j], __int_as_float(labels[j]));
    }

    floatx16 acc[2][2], acc2[2][2];
#pragma unroll
    for (int a = 0; a < 2; ++a)
#pragma unroll
        for (int b = 0; b < 2; ++b) { acc[a][b] = zerov(); acc2[a][b] = zerov(); }

    const _Float16* Abase  = &As [(wr * 64 + m) * SL + q * 8];
    const _Float16* Cbase  = &A2s[(wr * 64 + m) * SL + q * 8];
    const _Float16* Bbase  = &Bs [(wc * 64 + m) * SL + q * 8];

    for (int kc = 0; kc < D; kc += KC) {
        __syncthreads();
#pragma unroll
        for (int it = 0; it < 2; ++it) {
            int f = tid + it * 256;
            int row = f >> 2, g = f & 3;
            size_t go = (size_t)kc + g * 8;
            half8 v = *(const half8*)(xh + (size_t)(i0 + row) * D + go);
            *(half8*)(&As[row * SL + g * 8]) = v;
            half8 u = *(const half8*)(xh + (size_t)(j0 + row) * D + go);
            *(half8*)(&Bs[row * SL + g * 8]) = u;
            half8 t = *(const half8*)(xh + (size_t)sAnc[row] * D + go);
            *(half8*)(&A2s[row * SL + g * 8]) = t;
        }
        __syncthreads();
#pragma unroll
        for (int ks = 0; ks < KC; ks += 16) {
            half8 a0 = *(const half8*)(Abase + ks);
            half8 a1 = *(const half8*)(Abase + 32 * SL + ks);
            half8 c0 = *(const half8*)(Cbase + ks);
            half8 c1 = *(const half8*)(Cbase + 32 * SL + ks);
            half8 b0 = *(const half8*)(Bbase + ks);
            half8 b1 = *(const half8*)(Bbase + 32 * SL + ks);
            acc [0][0] = __builtin_amdgcn_mfma_f32_32x32x16_f16(a0, b0, acc [0][0], 0, 0, 0);
            acc [0][1] = __builtin_amdgcn_mfma_f32_32x32x16_f16(a0, b1, acc [0][1], 0, 0, 0);
            acc [1][0] = __builtin_amdgcn_mfma_f32_32x32x16_f16(a1, b0, acc [1][0], 0, 0, 0);
            acc [1][1] = __builtin_amdgcn_mfma_f32_32x32x16_f16(a1, b1, acc [1][1], 0, 0, 0);
            acc2[0][0] = __builtin_amdgcn_mfma_f32_32x32x16_f16(c0, b0, acc2[0][0], 0, 0, 0);
            acc2[0][1] = __builtin_amdgcn_mfma_f32_32x32x16_f16(c0, b1, acc2[0][1], 0, 0, 0);
            acc2[1][0] = __builtin_amdgcn_mfma_f32_32x32x16_f16(c1, b0, acc2[1][0], 0, 0, 0);
            acc2[1][1] = __builtin_amdgcn_mfma_f32_32x32x16_f16(c1, b1, acc2[1][1], 0, 0, 0);
        }
    }

    float sqj[2]; int labj[2];
#pragma unroll
    for (int tn = 0; tn < 2; ++tn) {
        float2 cj = colSL[wc * 64 + tn * 32 + m];
        sqj[tn] = cj.x; labj[tn] = __float_as_int(cj.y);
    }

    // per element: term2 t2 = 2*dot(i,j) + e2 - sq_j; term1 t1 = 2*dot(a_i,j) + e1 - sq_j
    // each contributes t iff 0 < t < alpha (and lab_i != lab_j)
    float local = 0.f;
#pragma unroll
    for (int tm = 0; tm < 2; ++tm) {
        int rbase = wr * 64 + tm * 32 + 4 * q;
#pragma unroll
        for (int rr = 0; rr < 16; ++rr) {
            int row = rbase + (rr & 3) + 8 * (rr >> 2);
            float4 re = rowE[row];
            int labi = __float_as_int(re.z);
#pragma unroll
            for (int tn = 0; tn < 2; ++tn) {
                if (labi != labj[tn]) {
                    float t2 = fmaf(2.f, acc [tm][tn][rr], re.x - sqj[tn]);
                    if (t2 > 0.f && t2 < ALPHA) local += t2;
                    float t1 = fmaf(2.f, acc2[tm][tn][rr], re.y - sqj[tn]);
                    if (t1 > 0.f && t1 < ALPHA) local += t1;
                }
            }
        }
    }
    block_reduce_write(local, &partials[blockIdx.y * gridDim.x + blockIdx.x], tid);
}

__global__ void k_final(const float* __restrict__ partials, float* __restrict__ out) {
    __shared__ double sred[4];
    int tid = threadIdx.x, lane = tid & 63;
    double s = 0.0;
    for (int t = tid; t < NPART; t += 256) s += (double)partials[t];
#pragma unroll
    for (int off = 32; off; off >>= 1) s += __shfl_down(s, off);
    if (lane == 0) sred[tid >> 6] = s;
    __syncthreads();
    if (tid == 0) out[0] = (float)(sred[0] + sred[1] + sred[2] + sred[3]);
}

// ---------------- launch ----------------

extern "C" void kernel_launch(void* const* d_in, const int* in_sizes, int n_in,
                              void* d_out, int out_size, void* d_ws, size_t ws_size,
                              hipStream_t stream) {
    const float* x = (const float*)d_in[0];
    const int* labels = (const int*)d_in[1];
    float* out = (float*)d_out;

    char* p = (char*)d_ws;
    int* anchor = (int*)p;            p += C * 4;
    float* sq = (float*)p;            p += N * 4;
    float* ap = (float*)p;            p += N * 4;
    float* partials = (float*)p;      p += NPART * 4;
    p = (char*)(((uintptr_t)p + 255) & ~(uintptr_t)255);
    _Float16* xh = (_Float16*)p;      // N*D*2 bytes

    k_init<<<1, 512, 0, stream>>>(anchor);
    k_prep<<<N / 4, 256, 0, stream>>>(x, labels, xh, sq, anchor);
    k_ap<<<N / 4, 256, 0, stream>>>(x, labels, anchor, sq, ap);

    dim3 g(N / BT, N / BT);
    k_fused<<<g, 256, 0, stream>>>(xh, labels, anchor, sq, ap, partials);
    k_final<<<1, 256, 0, stream>>>(partials, out);
}

// Round 5
// 147.067 us; speedup vs baseline: 1.8671x; 1.0180x over previous
//
#include <hip/hip_runtime.h>
#include <limits.h>
#include <stdint.h>

#define ALPHA 0.2f
#define HALFA 0.1f
static constexpr int N = 8192;
static constexpr int D = 128;
static constexpr int C = 512;
static constexpr int BT = 128;   // block tile (i and j)
static constexpr int KC = 64;    // k-chunk in fp16 elems (2 iters, 4 barriers)
static constexpr int SL = 72;    // LDS row stride in fp16 (64 + 8 pad; 4-way on reads, 16B-aligned)

using half8   = __attribute__((ext_vector_type(8))) _Float16;
using half2v  = __attribute__((ext_vector_type(2))) _Float16;
using floatx16 = __attribute__((ext_vector_type(16))) float;

__device__ __forceinline__ floatx16 zerov() { floatx16 v = {0.f}; return v; }

// ---------------- setup: 1 block computes all anchors + zeroes output ----------------

__global__ void k_anchor(const int* __restrict__ labels, int* __restrict__ anchor,
                         float* __restrict__ out) {
    __shared__ int sa[C];
    int t = threadIdx.x;           // 512 threads
    sa[t] = INT_MAX;
    __syncthreads();
    for (int i = t; i < N; i += 512) atomicMin(&sa[labels[i]], i);
    __syncthreads();
    anchor[t] = sa[t];
    if (t == 0) out[0] = 0.f;
}

// one wave per row: fp16 convert + sq[i] + ap[i] (anchor row reduced locally, fp32 exact)
__global__ void k_prep(const float* __restrict__ x, const int* __restrict__ labels,
                       const int* __restrict__ anchor, _Float16* __restrict__ xh,
                       float* __restrict__ sq, float* __restrict__ ap) {
    int row = (blockIdx.x * blockDim.x + threadIdx.x) >> 6;
    int lane = threadIdx.x & 63;
    int a = anchor[labels[row]];
    float2 v  = ((const float2*)(x + (size_t)row * D))[lane];
    float2 va = ((const float2*)(x + (size_t)a   * D))[lane];
    half2v h; h[0] = (_Float16)v.x; h[1] = (_Float16)v.y;
    *(half2v*)(xh + (size_t)row * D + lane * 2) = h;
    float s  = v.x * v.x + v.y * v.y;
    float sa = va.x * va.x + va.y * va.y;
    float dp = v.x * va.x + v.y * va.y;
#pragma unroll
    for (int off = 32; off; off >>= 1) {
        s  += __shfl_down(s,  off);
        sa += __shfl_down(sa, off);
        dp += __shfl_down(dp, off);
    }
    if (lane == 0) {
        sq[row] = s;
        ap[row] = sa + s - 2.0f * dp;
    }
}

// ---------------- fused term1+term2: dual-Gram MFMA, branch-free epilogue ----------------

__launch_bounds__(256)
__global__ void k_fused(const _Float16* __restrict__ xh, const int* __restrict__ labels,
                        const int* __restrict__ anchor, const float* __restrict__ sq,
                        const float* __restrict__ ap, float* __restrict__ out) {
    __shared__ __align__(16) _Float16 As [BT * SL];   // rows i0..
    __shared__ __align__(16) _Float16 A2s[BT * SL];   // anchor rows of lab(i0..)
    __shared__ __align__(16) _Float16 Bs [BT * SL];   // rows j0..
    __shared__ float4 rowE[BT];    // (e2' = ap+a/2-sq_i, e1' = ap+a/2-sq_a, lab bits, -)
    __shared__ float2 colSL[BT];   // (sq_j, lab_j bits)
    __shared__ int sAnc[BT];

    const int i0 = blockIdx.x * BT;
    const int j0 = blockIdx.y * BT;
    const int tid = threadIdx.x;
    const int lane = tid & 63, w = tid >> 6;
    const int wr = w >> 1, wc = w & 1;
    const int m = lane & 31, q = lane >> 5;

    if (tid < BT) {
        int i = i0 + tid;
        int li = labels[i];
        int a = anchor[li];
        sAnc[tid] = a;
        float e2, e1;
        if (i == a) { e2 = -1e30f; e1 = -1e30f; }   // anchors are not positives
        else {
            float base = ap[i] + HALFA;
            e2 = base - sq[i];
            e1 = base - sq[a];
        }
        rowE[tid] = make_float4(e2, e1, __int_as_float(li), 0.f);
    } else {
        int t = tid - BT;
        int j = j0 + t;
        colSL[t] = make_float2(sq[j], __int_as_float(labels[j]));
    }

    floatx16 acc[2][2], acc2[2][2];
#pragma unroll
    for (int a = 0; a < 2; ++a)
#pragma unroll
        for (int b = 0; b < 2; ++b) { acc[a][b] = zerov(); acc2[a][b] = zerov(); }

    const _Float16* Abase = &As [(wr * 64 + m) * SL + q * 8];
    const _Float16* Cbase = &A2s[(wr * 64 + m) * SL + q * 8];
    const _Float16* Bbase = &Bs [(wc * 64 + m) * SL + q * 8];

    for (int kc = 0; kc < D; kc += KC) {
        __syncthreads();
#pragma unroll
        for (int it = 0; it < 4; ++it) {
            int f = tid + it * 256;
            int row = f >> 3, g = f & 7;
            size_t go = (size_t)kc + g * 8;
            half8 v = *(const half8*)(xh + (size_t)(i0 + row) * D + go);
            *(half8*)(&As[row * SL + g * 8]) = v;
            half8 u = *(const half8*)(xh + (size_t)(j0 + row) * D + go);
            *(half8*)(&Bs[row * SL + g * 8]) = u;
            half8 t = *(const half8*)(xh + (size_t)sAnc[row] * D + go);
            *(half8*)(&A2s[row * SL + g * 8]) = t;
        }
        __syncthreads();
#pragma unroll
        for (int ks = 0; ks < KC; ks += 16) {
            half8 a0 = *(const half8*)(Abase + ks);
            half8 a1 = *(const half8*)(Abase + 32 * SL + ks);
            half8 c0 = *(const half8*)(Cbase + ks);
            half8 c1 = *(const half8*)(Cbase + 32 * SL + ks);
            half8 b0 = *(const half8*)(Bbase + ks);
            half8 b1 = *(const half8*)(Bbase + 32 * SL + ks);
            acc [0][0] = __builtin_amdgcn_mfma_f32_32x32x16_f16(a0, b0, acc [0][0], 0, 0, 0);
            acc [0][1] = __builtin_amdgcn_mfma_f32_32x32x16_f16(a0, b1, acc [0][1], 0, 0, 0);
            acc [1][0] = __builtin_amdgcn_mfma_f32_32x32x16_f16(a1, b0, acc [1][0], 0, 0, 0);
            acc [1][1] = __builtin_amdgcn_mfma_f32_32x32x16_f16(a1, b1, acc [1][1], 0, 0, 0);
            acc2[0][0] = __builtin_amdgcn_mfma_f32_32x32x16_f16(c0, b0, acc2[0][0], 0, 0, 0);
            acc2[0][1] = __builtin_amdgcn_mfma_f32_32x32x16_f16(c0, b1, acc2[0][1], 0, 0, 0);
            acc2[1][0] = __builtin_amdgcn_mfma_f32_32x32x16_f16(c1, b0, acc2[1][0], 0, 0, 0);
            acc2[1][1] = __builtin_amdgcn_mfma_f32_32x32x16_f16(c1, b1, acc2[1][1], 0, 0, 0);
        }
    }

    float sqj[2]; int labj[2];
#pragma unroll
    for (int tn = 0; tn < 2; ++tn) {
        float2 cj = colSL[wc * 64 + tn * 32 + m];
        sqj[tn] = cj.x; labj[tn] = __float_as_int(cj.y);
    }

    // hinge band-pass: u = 2*dot + e' - sq_j; contributes (u + a/2) iff |u| < a/2
    float local = 0.f;
#pragma unroll
    for (int tm = 0; tm < 2; ++tm) {
        int rbase = wr * 64 + tm * 32 + 4 * q;
#pragma unroll
        for (int rr = 0; rr < 16; ++rr) {
            int row = rbase + (rr & 3) + 8 * (rr >> 2);
            float4 re = rowE[row];
            int labi = __float_as_int(re.z);
#pragma unroll
            for (int tn = 0; tn < 2; ++tn) {
                if (labi != labj[tn]) {
                    float u2 = fmaf(2.f, acc [tm][tn][rr], re.x - sqj[tn]);
                    if (__builtin_fabsf(u2) < HALFA) local += u2 + HALFA;
                    float u1 = fmaf(2.f, acc2[tm][tn][rr], re.y - sqj[tn]);
                    if (__builtin_fabsf(u1) < HALFA) local += u1 + HALFA;
                }
            }
        }
    }

    // block reduce -> one float atomic into d_out (zeroed by k_anchor)
#pragma unroll
    for (int off = 32; off; off >>= 1) local += __shfl_down(local, off);
    __shared__ float wsum[4];
    if (lane == 0) wsum[w] = local;
    __syncthreads();
    if (tid == 0) atomicAdd(out, wsum[0] + wsum[1] + wsum[2] + wsum[3]);
}

// ---------------- launch ----------------

extern "C" void kernel_launch(void* const* d_in, const int* in_sizes, int n_in,
                              void* d_out, int out_size, void* d_ws, size_t ws_size,
                              hipStream_t stream) {
    const float* x = (const float*)d_in[0];
    const int* labels = (const int*)d_in[1];
    float* out = (float*)d_out;

    char* p = (char*)d_ws;
    int* anchor = (int*)p;            p += C * 4;
    float* sq = (float*)p;            p += N * 4;
    float* ap = (float*)p;            p += N * 4;
    p = (char*)(((uintptr_t)p + 255) & ~(uintptr_t)255);
    _Float16* xh = (_Float16*)p;      // N*D*2 bytes

    k_anchor<<<1, 512, 0, stream>>>(labels, anchor, out);
    k_prep<<<N / 4, 256, 0, stream>>>(x, labels, anchor, xh, sq, ap);
    dim3 g(N / BT, N / BT);
    k_fused<<<g, 256, 0, stream>>>(xh, labels, anchor, sq, ap, out);
}